// Round 1
// baseline (69605.658 us; speedup 1.0000x reference)
//
#include <hip/hip_runtime.h>
#include <math.h>

#define Bq 256
#define Tq 200
#define INq 33
#define Hq 2048
#define OUTq 4
#define NGEMM 512   // 8 row-tiles x 64 col-tiles, 32x32 each

// ---------------------------------------------------------------------------
// Output head for one timestep tp: out_o[:, tp, :] = softmax(h[:, tp, :] @ Wh2o^T)
// 4 workgroups x 256 threads; 4 threads cooperate per batch row (K split 4x512),
// fixed-order shuffle reduction -> deterministic.
// ---------------------------------------------------------------------------
__device__ __forceinline__ void proj_block(int p, int tid, int tp,
    const float* __restrict__ out_h, const float* __restrict__ Wh2o,
    float* __restrict__ out_o)
{
  const int r  = p * 64 + (tid >> 2);   // batch row 0..255
  const int p4 = tid & 3;               // K-partition
  const float* hp = out_h + ((size_t)r * Tq + tp) * Hq;
  float acc0 = 0.f, acc1 = 0.f, acc2 = 0.f, acc3 = 0.f;
  const int k0 = p4 * 512;
#pragma unroll 4
  for (int k = k0; k < k0 + 512; k += 4) {
    float4 hv = *(const float4*)(hp + k);
    float4 w0 = *(const float4*)(Wh2o + 0 * Hq + k);
    float4 w1 = *(const float4*)(Wh2o + 1 * Hq + k);
    float4 w2 = *(const float4*)(Wh2o + 2 * Hq + k);
    float4 w3 = *(const float4*)(Wh2o + 3 * Hq + k);
    acc0 = fmaf(hv.x, w0.x, fmaf(hv.y, w0.y, fmaf(hv.z, w0.z, fmaf(hv.w, w0.w, acc0))));
    acc1 = fmaf(hv.x, w1.x, fmaf(hv.y, w1.y, fmaf(hv.z, w1.z, fmaf(hv.w, w1.w, acc1))));
    acc2 = fmaf(hv.x, w2.x, fmaf(hv.y, w2.y, fmaf(hv.z, w2.z, fmaf(hv.w, w2.w, acc2))));
    acc3 = fmaf(hv.x, w3.x, fmaf(hv.y, w3.y, fmaf(hv.z, w3.z, fmaf(hv.w, w3.w, acc3))));
  }
  // reduce across the 4 K-partitions (lanes tid&3 within the same wave)
  acc0 += __shfl_xor(acc0, 1); acc1 += __shfl_xor(acc1, 1);
  acc2 += __shfl_xor(acc2, 1); acc3 += __shfl_xor(acc3, 1);
  acc0 += __shfl_xor(acc0, 2); acc1 += __shfl_xor(acc1, 2);
  acc2 += __shfl_xor(acc2, 2); acc3 += __shfl_xor(acc3, 2);
  if (p4 == 0) {
    float m  = fmaxf(fmaxf(acc0, acc1), fmaxf(acc2, acc3));
    float e0 = expf(acc0 - m), e1 = expf(acc1 - m);
    float e2 = expf(acc2 - m), e3 = expf(acc3 - m);
    float inv = 1.0f / (e0 + e1 + e2 + e3);
    float* op = out_o + ((size_t)r * Tq + tp) * OUTq;
    op[0] = e0 * inv; op[1] = e1 * inv; op[2] = e2 * inv; op[3] = e3 * inv;
  }
}

// ---------------------------------------------------------------------------
// One recurrent step t:
//   pre = x[:,t,:]@Wi2h^T + h_{t-1}@Wrec^T + noise[t]
//   h_t = 0.1*relu(pre) + 0.9*h_{t-1}        -> stored to hiddens[:, t, :]
// plus (in 4 extra WGs) the softmax head for step t-1.
// h_{t-1} is read from the hiddens output written by the previous launch.
// ---------------------------------------------------------------------------
__global__ __launch_bounds__(256) void rnn_step(
    const float* __restrict__ x, const float* __restrict__ noise,
    const float* __restrict__ Wi2h, const float* __restrict__ Wrec,
    const float* __restrict__ Wh2o, float* __restrict__ out_h,
    float* __restrict__ out_o, int t)
{
  const int wg  = blockIdx.x;
  const int tid = threadIdx.x;

  if (wg >= NGEMM) {               // output-head workgroups (for step t-1)
    if (t > 0) proj_block(wg - NGEMM, tid, t - 1, out_h, Wh2o, out_o);
    return;
  }

  // ---- 32x32 GEMM tile, 2x2 register block per thread ----
  const int tileRow = wg >> 6;     // 0..7   (batch tiles)
  const int tileCol = wg & 63;     // 0..63  (hidden tiles)
  const int tx = tid & 15;         // hidden-pair index
  const int ty = tid >> 4;         // batch-pair index
  const int b0 = tileRow * 32 + ty * 2;
  const int j0 = tileCol * 32 + tx * 2;

  float acc00 = 0.f, acc01 = 0.f, acc10 = 0.f, acc11 = 0.f;

  if (t > 0) {
    const float* a0 = out_h + ((size_t)b0 * Tq + (t - 1)) * Hq;
    const float* a1 = a0 + (size_t)Tq * Hq;
    const float* w0 = Wrec + (size_t)j0 * Hq;
    const float* w1 = w0 + Hq;
#pragma unroll 2
    for (int k = 0; k < Hq; k += 4) {
      float4 av0 = *(const float4*)(a0 + k);
      float4 av1 = *(const float4*)(a1 + k);
      float4 wv0 = *(const float4*)(w0 + k);
      float4 wv1 = *(const float4*)(w1 + k);
      acc00 = fmaf(av0.x, wv0.x, acc00); acc00 = fmaf(av0.y, wv0.y, acc00);
      acc00 = fmaf(av0.z, wv0.z, acc00); acc00 = fmaf(av0.w, wv0.w, acc00);
      acc01 = fmaf(av0.x, wv1.x, acc01); acc01 = fmaf(av0.y, wv1.y, acc01);
      acc01 = fmaf(av0.z, wv1.z, acc01); acc01 = fmaf(av0.w, wv1.w, acc01);
      acc10 = fmaf(av1.x, wv0.x, acc10); acc10 = fmaf(av1.y, wv0.y, acc10);
      acc10 = fmaf(av1.z, wv0.z, acc10); acc10 = fmaf(av1.w, wv0.w, acc10);
      acc11 = fmaf(av1.x, wv1.x, acc11); acc11 = fmaf(av1.y, wv1.y, acc11);
      acc11 = fmaf(av1.z, wv1.z, acc11); acc11 = fmaf(av1.w, wv1.w, acc11);
    }
  }

  // ---- fused input projection: += x[b, t, :] @ Wi2h[j, :]^T  (IN = 33) ----
  {
    const float* xr0 = x + ((size_t)b0 * Tq + t) * INq;
    const float* xr1 = xr0 + (size_t)Tq * INq;
    const float* wi0 = Wi2h + (size_t)j0 * INq;
    const float* wi1 = wi0 + INq;
#pragma unroll
    for (int i = 0; i < INq; ++i) {
      float x0 = xr0[i], x1 = xr1[i];
      float u0 = wi0[i], u1 = wi1[i];
      acc00 = fmaf(x0, u0, acc00);
      acc01 = fmaf(x0, u1, acc01);
      acc10 = fmaf(x1, u0, acc10);
      acc11 = fmaf(x1, u1, acc11);
    }
  }

  // ---- noise, leaky decay, store h_t ----
  float hp00 = 0.f, hp01 = 0.f, hp10 = 0.f, hp11 = 0.f;
  if (t > 0) {
    const float* hpp0 = out_h + ((size_t)b0 * Tq + (t - 1)) * Hq + j0;
    const float* hpp1 = hpp0 + (size_t)Tq * Hq;
    float2 h0 = *(const float2*)hpp0;
    float2 h1 = *(const float2*)hpp1;
    hp00 = h0.x; hp01 = h0.y; hp10 = h1.x; hp11 = h1.y;
  }
  const float* nz0 = noise + ((size_t)t * Bq + b0) * Hq + j0;
  const float* nz1 = nz0 + Hq;
  float2 n0 = *(const float2*)nz0;
  float2 n1 = *(const float2*)nz1;

  float pre00 = acc00 + n0.x, pre01 = acc01 + n0.y;
  float pre10 = acc10 + n1.x, pre11 = acc11 + n1.y;

  float h00 = fmaf(fmaxf(pre00, 0.f), 0.1f, 0.9f * hp00);
  float h01 = fmaf(fmaxf(pre01, 0.f), 0.1f, 0.9f * hp01);
  float h10 = fmaf(fmaxf(pre10, 0.f), 0.1f, 0.9f * hp10);
  float h11 = fmaf(fmaxf(pre11, 0.f), 0.1f, 0.9f * hp11);

  float* o0 = out_h + ((size_t)b0 * Tq + t) * Hq + j0;
  float* o1 = o0 + (size_t)Tq * Hq;
  *(float2*)o0 = make_float2(h00, h01);
  *(float2*)o1 = make_float2(h10, h11);
}

// tail: output head for the final timestep
__global__ __launch_bounds__(256) void proj_tail(
    const float* __restrict__ out_h, const float* __restrict__ Wh2o,
    float* __restrict__ out_o)
{
  proj_block(blockIdx.x, threadIdx.x, Tq - 1, out_h, Wh2o, out_o);
}

extern "C" void kernel_launch(void* const* d_in, const int* in_sizes, int n_in,
                              void* d_out, int out_size, void* d_ws, size_t ws_size,
                              hipStream_t stream) {
  const float* x     = (const float*)d_in[0];
  const float* noise = (const float*)d_in[1];
  const float* Wi2h  = (const float*)d_in[2];
  const float* Wrec  = (const float*)d_in[3];
  const float* Wh2o  = (const float*)d_in[4];
  float* out_h = (float*)d_out;
  float* out_o = out_h + (size_t)Bq * Tq * Hq;

  for (int t = 0; t < Tq; ++t) {
    rnn_step<<<NGEMM + 4, 256, 0, stream>>>(x, noise, Wi2h, Wrec, Wh2o,
                                            out_h, out_o, t);
  }
  proj_tail<<<4, 256, 0, stream>>>(out_h, Wh2o, out_o);
}

// Round 2
// 23487.325 us; speedup vs baseline: 2.9635x; 2.9635x over previous
//
#include <hip/hip_runtime.h>
#include <math.h>

#define Bq 256
#define Tq 200
#define INq 33
#define Hq 2048
#define OUTq 4

#define BM 32
#define BN 64
#define BKq 32
#define HALFK 1024
#define NSTEPS (HALFK / BKq)   // 32
#define NGEMM 256              // 8 row-tiles x 32 col-tiles

// ---------------------------------------------------------------------------
// Output head for timestep tp: out_o[:, tp, :] = softmax(h[:, tp, :] @ Wh2o^T)
// 4 WGs, first 256 threads each; 4 threads per batch row, fixed-order reduce.
// ---------------------------------------------------------------------------
__device__ __forceinline__ void proj_block(int p, int tid, int tp,
    const float* __restrict__ out_h, const float* __restrict__ Wh2o,
    float* __restrict__ out_o)
{
  const int r  = p * 64 + (tid >> 2);
  const int p4 = tid & 3;
  const float* hp = out_h + ((size_t)r * Tq + tp) * Hq;
  float acc0 = 0.f, acc1 = 0.f, acc2 = 0.f, acc3 = 0.f;
  const int k0 = p4 * 512;
#pragma unroll 4
  for (int k = k0; k < k0 + 512; k += 4) {
    float4 hv = *(const float4*)(hp + k);
    float4 w0 = *(const float4*)(Wh2o + 0 * Hq + k);
    float4 w1 = *(const float4*)(Wh2o + 1 * Hq + k);
    float4 w2 = *(const float4*)(Wh2o + 2 * Hq + k);
    float4 w3 = *(const float4*)(Wh2o + 3 * Hq + k);
    acc0 = fmaf(hv.x, w0.x, fmaf(hv.y, w0.y, fmaf(hv.z, w0.z, fmaf(hv.w, w0.w, acc0))));
    acc1 = fmaf(hv.x, w1.x, fmaf(hv.y, w1.y, fmaf(hv.z, w1.z, fmaf(hv.w, w1.w, acc1))));
    acc2 = fmaf(hv.x, w2.x, fmaf(hv.y, w2.y, fmaf(hv.z, w2.z, fmaf(hv.w, w2.w, acc2))));
    acc3 = fmaf(hv.x, w3.x, fmaf(hv.y, w3.y, fmaf(hv.z, w3.z, fmaf(hv.w, w3.w, acc3))));
  }
  acc0 += __shfl_xor(acc0, 1); acc1 += __shfl_xor(acc1, 1);
  acc2 += __shfl_xor(acc2, 1); acc3 += __shfl_xor(acc3, 1);
  acc0 += __shfl_xor(acc0, 2); acc1 += __shfl_xor(acc1, 2);
  acc2 += __shfl_xor(acc2, 2); acc3 += __shfl_xor(acc3, 2);
  if (p4 == 0) {
    float m  = fmaxf(fmaxf(acc0, acc1), fmaxf(acc2, acc3));
    float e0 = expf(acc0 - m), e1 = expf(acc1 - m);
    float e2 = expf(acc2 - m), e3 = expf(acc3 - m);
    float inv = 1.0f / (e0 + e1 + e2 + e3);
    float* op = out_o + ((size_t)r * Tq + tp) * OUTq;
    op[0] = e0 * inv; op[1] = e1 * inv; op[2] = e2 * inv; op[3] = e3 * inv;
  }
}

// ---------------------------------------------------------------------------
// One step: h_t = 0.1*relu(x_t@Wi2h^T + h_{t-1}@Wrec^T + nz) + 0.9*h_{t-1}
// 512 threads: waves 0-3 (half 0) do k in [0,1024), waves 4-7 (half 1) do
// k in [1024,2048) + the IN=33 input projection; combined via LDS (fixed
// order -> deterministic). LDS double-buffered, transposed tiles so inner
// reads are broadcast b64/b128 (conflict-free).
// ---------------------------------------------------------------------------
__global__ __launch_bounds__(512) void rnn_step(
    const float* __restrict__ x, const float* __restrict__ noise,
    const float* __restrict__ Wi2h, const float* __restrict__ Wrec,
    const float* __restrict__ Wh2o, float* __restrict__ out_h,
    float* __restrict__ out_o, int t)
{
  __shared__ float As[2][2][BKq][BM];   // [half][buf][k][m]  16 KB
  __shared__ float Bs[2][2][BKq][BN];   // [half][buf][k][n]  32 KB
  __shared__ float Red[8][256];         // split-K combine     8 KB

  const int wg  = blockIdx.x;
  const int tid = threadIdx.x;

  if (wg >= NGEMM) {                    // softmax head for step t-1
    if (t > 0 && tid < 256) proj_block(wg - NGEMM, tid, t - 1, out_h, Wh2o, out_o);
    return;
  }

  // XCD-chunked swizzle: XCD c gets logical blocks [32c,32c+32) = 4 col-tiles
  const int L = (wg & 7) * 32 + (wg >> 3);
  const int tileCol = L >> 3;           // 0..31
  const int tileRow = L & 7;            // 0..7

  const int half = tid >> 8;            // 0/1 -> K half
  const int ht   = tid & 255;
  const int tx   = ht & 15;             // n-quad
  const int ty   = ht >> 4;             // m-pair
  const int b0   = tileRow * BM + ty * 2;
  const int j0   = tileCol * BN + tx * 4;
  const int kb   = half * HALFK;

  float acc00 = 0.f, acc01 = 0.f, acc02 = 0.f, acc03 = 0.f;
  float acc10 = 0.f, acc11 = 0.f, acc12 = 0.f, acc13 = 0.f;

  if (t > 0) {
    const int sa_b  = ht & 31;          // A staging: row, k-quad
    const int sa_kq = ht >> 5;          // 0..7
    const int sb_j  = ht & 63;          // B staging: row, k-oct
    const int sb_kh = ht >> 6;          // 0..3
    const float* Ag = out_h + ((size_t)(tileRow * BM + sa_b) * Tq + (t - 1)) * Hq + kb + sa_kq * 4;
    const float* Bg = Wrec + (size_t)(tileCol * BN + sb_j) * Hq + kb + sb_kh * 8;

    // prologue: stage buf 0
    {
      float4 ra  = *(const float4*)(Ag);
      float4 rb0 = *(const float4*)(Bg);
      float4 rb1 = *(const float4*)(Bg + 4);
      As[half][0][sa_kq * 4 + 0][sa_b] = ra.x;
      As[half][0][sa_kq * 4 + 1][sa_b] = ra.y;
      As[half][0][sa_kq * 4 + 2][sa_b] = ra.z;
      As[half][0][sa_kq * 4 + 3][sa_b] = ra.w;
      Bs[half][0][sb_kh * 8 + 0][sb_j] = rb0.x;
      Bs[half][0][sb_kh * 8 + 1][sb_j] = rb0.y;
      Bs[half][0][sb_kh * 8 + 2][sb_j] = rb0.z;
      Bs[half][0][sb_kh * 8 + 3][sb_j] = rb0.w;
      Bs[half][0][sb_kh * 8 + 4][sb_j] = rb1.x;
      Bs[half][0][sb_kh * 8 + 5][sb_j] = rb1.y;
      Bs[half][0][sb_kh * 8 + 6][sb_j] = rb1.z;
      Bs[half][0][sb_kh * 8 + 7][sb_j] = rb1.w;
    }
    __syncthreads();

    for (int s = 0; s < NSTEPS; ++s) {
      const int buf = s & 1;
      float4 na, nb0, nb1;
      if (s + 1 < NSTEPS) {             // issue next-tile loads early
        na  = *(const float4*)(Ag + (s + 1) * BKq);
        nb0 = *(const float4*)(Bg + (s + 1) * BKq);
        nb1 = *(const float4*)(Bg + (s + 1) * BKq + 4);
      }
#pragma unroll
      for (int k = 0; k < BKq; ++k) {
        float2 a = *(const float2*)&As[half][buf][k][ty * 2];
        float4 b = *(const float4*)&Bs[half][buf][k][tx * 4];
        acc00 = fmaf(a.x, b.x, acc00); acc01 = fmaf(a.x, b.y, acc01);
        acc02 = fmaf(a.x, b.z, acc02); acc03 = fmaf(a.x, b.w, acc03);
        acc10 = fmaf(a.y, b.x, acc10); acc11 = fmaf(a.y, b.y, acc11);
        acc12 = fmaf(a.y, b.z, acc12); acc13 = fmaf(a.y, b.w, acc13);
      }
      if (s + 1 < NSTEPS) {             // write next tile (other buffer)
        const int nb = buf ^ 1;
        As[half][nb][sa_kq * 4 + 0][sa_b] = na.x;
        As[half][nb][sa_kq * 4 + 1][sa_b] = na.y;
        As[half][nb][sa_kq * 4 + 2][sa_b] = na.z;
        As[half][nb][sa_kq * 4 + 3][sa_b] = na.w;
        Bs[half][nb][sb_kh * 8 + 0][sb_j] = nb0.x;
        Bs[half][nb][sb_kh * 8 + 1][sb_j] = nb0.y;
        Bs[half][nb][sb_kh * 8 + 2][sb_j] = nb0.z;
        Bs[half][nb][sb_kh * 8 + 3][sb_j] = nb0.w;
        Bs[half][nb][sb_kh * 8 + 4][sb_j] = nb1.x;
        Bs[half][nb][sb_kh * 8 + 5][sb_j] = nb1.y;
        Bs[half][nb][sb_kh * 8 + 6][sb_j] = nb1.z;
        Bs[half][nb][sb_kh * 8 + 7][sb_j] = nb1.w;
      }
      __syncthreads();
    }
  }

  // half 1: fused input projection (IN = 33), then dump accs to LDS
  if (half == 1) {
    const float* xr0 = x + ((size_t)b0 * Tq + t) * INq;
    const float* xr1 = xr0 + (size_t)Tq * INq;
    const float* wi  = Wi2h + (size_t)j0 * INq;
#pragma unroll
    for (int i = 0; i < INq; ++i) {
      float x0 = xr0[i], x1 = xr1[i];
      float u0 = wi[i], u1 = wi[INq + i], u2 = wi[2 * INq + i], u3 = wi[3 * INq + i];
      acc00 = fmaf(x0, u0, acc00); acc01 = fmaf(x0, u1, acc01);
      acc02 = fmaf(x0, u2, acc02); acc03 = fmaf(x0, u3, acc03);
      acc10 = fmaf(x1, u0, acc10); acc11 = fmaf(x1, u1, acc11);
      acc12 = fmaf(x1, u2, acc12); acc13 = fmaf(x1, u3, acc13);
    }
    Red[0][ht] = acc00; Red[1][ht] = acc01; Red[2][ht] = acc02; Red[3][ht] = acc03;
    Red[4][ht] = acc10; Red[5][ht] = acc11; Red[6][ht] = acc12; Red[7][ht] = acc13;
  }
  __syncthreads();

  if (half == 0) {
    acc00 += Red[0][ht]; acc01 += Red[1][ht]; acc02 += Red[2][ht]; acc03 += Red[3][ht];
    acc10 += Red[4][ht]; acc11 += Red[5][ht]; acc12 += Red[6][ht]; acc13 += Red[7][ht];

    float4 hp0 = make_float4(0.f, 0.f, 0.f, 0.f);
    float4 hp1 = make_float4(0.f, 0.f, 0.f, 0.f);
    if (t > 0) {
      hp0 = *(const float4*)(out_h + ((size_t)b0 * Tq + (t - 1)) * Hq + j0);
      hp1 = *(const float4*)(out_h + ((size_t)(b0 + 1) * Tq + (t - 1)) * Hq + j0);
    }
    float4 n0 = *(const float4*)(noise + ((size_t)t * Bq + b0) * Hq + j0);
    float4 n1 = *(const float4*)(noise + ((size_t)t * Bq + b0 + 1) * Hq + j0);

    float4 o0, o1;
    o0.x = fmaf(fmaxf(acc00 + n0.x, 0.f), 0.1f, 0.9f * hp0.x);
    o0.y = fmaf(fmaxf(acc01 + n0.y, 0.f), 0.1f, 0.9f * hp0.y);
    o0.z = fmaf(fmaxf(acc02 + n0.z, 0.f), 0.1f, 0.9f * hp0.z);
    o0.w = fmaf(fmaxf(acc03 + n0.w, 0.f), 0.1f, 0.9f * hp0.w);
    o1.x = fmaf(fmaxf(acc10 + n1.x, 0.f), 0.1f, 0.9f * hp1.x);
    o1.y = fmaf(fmaxf(acc11 + n1.y, 0.f), 0.1f, 0.9f * hp1.y);
    o1.z = fmaf(fmaxf(acc12 + n1.z, 0.f), 0.1f, 0.9f * hp1.z);
    o1.w = fmaf(fmaxf(acc13 + n1.w, 0.f), 0.1f, 0.9f * hp1.w);

    *(float4*)(out_h + ((size_t)b0 * Tq + t) * Hq + j0) = o0;
    *(float4*)(out_h + ((size_t)(b0 + 1) * Tq + t) * Hq + j0) = o1;
  }
}

// tail: output head for the final timestep
__global__ __launch_bounds__(256) void proj_tail(
    const float* __restrict__ out_h, const float* __restrict__ Wh2o,
    float* __restrict__ out_o)
{
  proj_block(blockIdx.x, threadIdx.x, Tq - 1, out_h, Wh2o, out_o);
}

extern "C" void kernel_launch(void* const* d_in, const int* in_sizes, int n_in,
                              void* d_out, int out_size, void* d_ws, size_t ws_size,
                              hipStream_t stream) {
  const float* x     = (const float*)d_in[0];
  const float* noise = (const float*)d_in[1];
  const float* Wi2h  = (const float*)d_in[2];
  const float* Wrec  = (const float*)d_in[3];
  const float* Wh2o  = (const float*)d_in[4];
  float* out_h = (float*)d_out;
  float* out_o = out_h + (size_t)Bq * Tq * Hq;

  for (int t = 0; t < Tq; ++t) {
    rnn_step<<<NGEMM + 4, 512, 0, stream>>>(x, noise, Wi2h, Wrec, Wh2o,
                                            out_h, out_o, t);
  }
  proj_tail<<<4, 256, 0, stream>>>(out_h, Wh2o, out_o);
}